// Round 1
// baseline (1379.747 us; speedup 1.0000x reference)
//
#include <hip/hip_runtime.h>
#include <math.h>

#define BATCH 8
#define NPTS 2048
#define CH 64
#define KNB 16
#define M_SAMPLES (BATCH * NPTS * KNB)   // 262144

// ws layout (floats):
//   rel    : [0, 786432)                 262144 * 3
//   part1  : [786432, 791040)            512 blocks * 9
//   s1t1   : [791040, 791168)            64 scale + 64 shift
//   part2  : [791168, 823936)            256 blocks * 128
//   s2t2   : [823936, 824064)
// total ~3.30 MB

#define WS_REL   0
#define WS_PART1 786432
#define WS_S1T1  791040
#define WS_PART2 791168
#define WS_S2T2  823936

// ---------------- K1: KNN + rel + BN1 moment partials ----------------
// grid 512 (= 8 batches * 64 query-blocks of 32), block 128 (32 queries * 4 parts)
__global__ __launch_bounds__(128) void knn_rel_kernel(const float* __restrict__ xyz,
                                                      float* __restrict__ rel,
                                                      float* __restrict__ part1) {
    __shared__ float4 pts[NPTS];        // x,y,z,|p|^2  (32 KB)
    __shared__ float dl[128 * 17];
    __shared__ int   il[128 * 17];
    __shared__ float red[9 * 32];

    const int b    = blockIdx.x >> 6;
    const int qblk = blockIdx.x & 63;
    const int tid  = threadIdx.x;
    const float* xb = xyz + (size_t)b * 3 * NPTS;
    for (int j = tid; j < NPTS; j += 128) {
        float x = xb[j], y = xb[NPTS + j], z = xb[2 * NPTS + j];
        float sq = (x * x + y * y) + z * z;   // match np: sum(p*p) left fold
        pts[j] = make_float4(x, y, z, sq);
    }
    __syncthreads();

    const int q    = qblk * 32 + (tid >> 2);
    const int part = tid & 3;
    const float4 pq = pts[q];
    float* mydl = dl + tid * 17;
    int*   myil = il + tid * 17;
#pragma unroll
    for (int m = 0; m < 17; ++m) { mydl[m] = INFINITY; myil[m] = 0x7fffffff; }
    float worst = INFINITY; int worsti = 0x7fffffff;
    const int jbase = part * 512;
#pragma unroll 4
    for (int t = 0; t < 512; ++t) {
        int j = jbase + ((t + part * 127) & 511);    // stagger to avoid LDS bank aliasing
        float4 pj = pts[j];
        float dot = pq.x * pj.x + pq.y * pj.y + pq.z * pj.z;
        float d2 = (pq.w + pj.w) - 2.0f * dot;       // same formula as reference
        if (j == q) continue;
        if (d2 < worst || (d2 == worst && j < worsti)) {
            int m = 15;
            while (m > 0) {
                float dm = mydl[m - 1]; int im = myil[m - 1];
                if (d2 < dm || (d2 == dm && j < im)) { mydl[m] = dm; myil[m] = im; --m; }
                else break;
            }
            mydl[m] = d2; myil[m] = j;
            worst = mydl[15]; worsti = myil[15];
        }
    }
    __syncthreads();

    float acc[9] = {0.f,0.f,0.f,0.f,0.f,0.f,0.f,0.f,0.f};
    if (part == 0) {
        // merge the 4 sorted lists of this query; lexicographic (d2, idx)
        const float* l0 = dl + tid * 17;        const int* i0 = il + tid * 17;
        const float* l1 = l0 + 17;              const int* i1 = i0 + 17;
        const float* l2 = l1 + 17;              const int* i2 = i1 + 17;
        const float* l3 = l2 + 17;              const int* i3 = i2 + 17;
        int h0 = 0, h1 = 0, h2 = 0, h3 = 0;
        const size_t relbase = ((size_t)(b * NPTS + q)) * KNB * 3;
        for (int k = 0; k < KNB; ++k) {
            float bd = l0[h0]; int bi = i0[h0]; int bp = 0;
            float dv = l1[h1]; int iv = i1[h1];
            if (dv < bd || (dv == bd && iv < bi)) { bd = dv; bi = iv; bp = 1; }
            dv = l2[h2]; iv = i2[h2];
            if (dv < bd || (dv == bd && iv < bi)) { bd = dv; bi = iv; bp = 2; }
            dv = l3[h3]; iv = i3[h3];
            if (dv < bd || (dv == bd && iv < bi)) { bd = dv; bi = iv; bp = 3; }
            if      (bp == 0) ++h0;
            else if (bp == 1) ++h1;
            else if (bp == 2) ++h2;
            else              ++h3;
            float4 pn = pts[bi];
            float r0 = pn.x - pq.x, r1 = pn.y - pq.y, r2 = pn.z - pq.z;
            rel[relbase + k * 3 + 0] = r0;
            rel[relbase + k * 3 + 1] = r1;
            rel[relbase + k * 3 + 2] = r2;
            acc[0] += r0; acc[1] += r1; acc[2] += r2;
            acc[3] += r0 * r0; acc[4] += r0 * r1; acc[5] += r0 * r2;
            acc[6] += r1 * r1; acc[7] += r1 * r2; acc[8] += r2 * r2;
        }
    }
    __syncthreads();
    if (part == 0) {
        int g = tid >> 2;
#pragma unroll
        for (int v = 0; v < 9; ++v) red[v * 32 + g] = acc[v];
    }
    __syncthreads();
    if (tid < 9) {
        float s = 0.f;
        for (int g = 0; g < 32; ++g) s += red[tid * 32 + g];
        part1[blockIdx.x * 9 + tid] = s;
    }
}

// ---------------- K2: finalize BN1 affine (closed form from rel moments) ----------------
__global__ void fin1_kernel(const float* __restrict__ part1,
                            const float* __restrict__ W1, const float* __restrict__ b1,
                            const float* __restrict__ gamma, const float* __restrict__ beta,
                            float* __restrict__ s1t1) {
    __shared__ double sm[9];
    int t = threadIdx.x;
    if (t < 9) {
        double s = 0.0;
        for (int i = 0; i < 512; ++i) s += (double)part1[i * 9 + t];
        sm[t] = s;
    }
    __syncthreads();
    const double Md = (double)M_SAMPLES;
    double mu0 = sm[0] / Md, mu1 = sm[1] / Md, mu2 = sm[2] / Md;
    double C00 = sm[3] / Md - mu0 * mu0;
    double C01 = sm[4] / Md - mu0 * mu1;
    double C02 = sm[5] / Md - mu0 * mu2;
    double C11 = sm[6] / Md - mu1 * mu1;
    double C12 = sm[7] / Md - mu1 * mu2;
    double C22 = sm[8] / Md - mu2 * mu2;
    double w0 = (double)W1[t * 3], w1 = (double)W1[t * 3 + 1], w2 = (double)W1[t * 3 + 2];
    double mean = w0 * mu0 + w1 * mu1 + w2 * mu2 + (double)b1[t];
    double var  = w0 * w0 * C00 + w1 * w1 * C11 + w2 * w2 * C22
                + 2.0 * (w0 * w1 * C01 + w0 * w2 * C02 + w1 * w2 * C12);
    double sc = (double)gamma[t] / sqrt(var + 1e-5);
    s1t1[t]      = (float)sc;
    s1t1[64 + t] = (float)((double)beta[t] - mean * sc);
}

// ---------------- K3: BN2 statistics (sum, sumsq of h2 per channel) ----------------
// grid 256, block 256, 4 sample-iters per block
__global__ __launch_bounds__(256) void stats2_kernel(const float* __restrict__ rel,
        const float* __restrict__ W1, const float* __restrict__ b1,
        const float* __restrict__ W2, const float* __restrict__ b2,
        const float* __restrict__ s1t1, float* __restrict__ part2) {
    __shared__ float  W2l[64 * 64];
    __shared__ float4 W1l[64];
    __shared__ float2 st1[64];
    __shared__ float  b2l[64];
    __shared__ float  acc[4][128];
    const int tid = threadIdx.x;
    for (int i = tid; i < 4096; i += 256) W2l[i] = W2[i];
    if (tid < 64) {
        W1l[tid] = make_float4(W1[tid * 3], W1[tid * 3 + 1], W1[tid * 3 + 2], b1[tid]);
        st1[tid] = make_float2(s1t1[tid], s1t1[64 + tid]);
        b2l[tid] = b2[tid];
    }
    for (int i = tid; i < 512; i += 256) ((float*)acc)[i] = 0.f;
    __syncthreads();
    const int wave = tid >> 6, lane = tid & 63;
    for (int it = 0; it < 4; ++it) {
        const int s = (blockIdx.x * 4 + it) * 256 + tid;
        float r0 = rel[s * 3], r1 = rel[s * 3 + 1], r2 = rel[s * 3 + 2];
        float a[64];
#pragma unroll
        for (int c = 0; c < 64; ++c) {
            float4 w = W1l[c];
            float h = (w.x * r0 + w.y * r1 + w.z * r2) + w.w;
            float2 st = st1[c];
            a[c] = fmaxf(fmaf(st.x, h, st.y), 0.f);
        }
#pragma unroll 1
        for (int o = 0; o < 64; ++o) {
            float h2 = b2l[o];
#pragma unroll
            for (int c = 0; c < 64; c += 4) {
                float4 w = *(const float4*)&W2l[o * 64 + c];
                h2 = fmaf(w.x, a[c], h2);     h2 = fmaf(w.y, a[c + 1], h2);
                h2 = fmaf(w.z, a[c + 2], h2); h2 = fmaf(w.w, a[c + 3], h2);
            }
            float sq = h2 * h2;
#pragma unroll
            for (int d = 1; d < 64; d <<= 1) {
                h2 += __shfl_xor(h2, d, 64);
                sq += __shfl_xor(sq, d, 64);
            }
            if (lane == 0) { acc[wave][o * 2] += h2; acc[wave][o * 2 + 1] += sq; }
        }
    }
    __syncthreads();
    if (tid < 128)
        part2[blockIdx.x * 128 + tid] = acc[0][tid] + acc[1][tid] + acc[2][tid] + acc[3][tid];
}

// ---------------- K4: finalize BN2 affine ----------------
__global__ void fin2_kernel(const float* __restrict__ part2,
                            const float* __restrict__ gamma, const float* __restrict__ beta,
                            float* __restrict__ s2t2) {
    int o = threadIdx.x;
    double s = 0.0, sq = 0.0;
    for (int i = 0; i < 256; ++i) {
        s  += (double)part2[i * 128 + o * 2];
        sq += (double)part2[i * 128 + o * 2 + 1];
    }
    const double Md = (double)M_SAMPLES;
    double mean = s / Md;
    double var  = sq / Md - mean * mean;
    double sc = (double)gamma[o] / sqrt(var + 1e-5);
    s2t2[o]      = (float)sc;
    s2t2[64 + o] = (float)((double)beta[o] - mean * sc);
}

// ---------------- K5: full chain + max over k, write [B,C,N] ----------------
// grid 1024, block 256; wave = 4 (b,n) pairs x 16 k
__global__ __launch_bounds__(256) void out_kernel(const float* __restrict__ rel,
        const float* __restrict__ W1, const float* __restrict__ b1,
        const float* __restrict__ W2, const float* __restrict__ b2,
        const float* __restrict__ s1t1, const float* __restrict__ s2t2,
        float* __restrict__ out) {
    __shared__ float  W2l[64 * 64];
    __shared__ float4 W1l[64];
    __shared__ float2 st1[64];
    __shared__ float2 st2[64];
    __shared__ float  b2l[64];
    const int tid = threadIdx.x;
    for (int i = tid; i < 4096; i += 256) W2l[i] = W2[i];
    if (tid < 64) {
        W1l[tid] = make_float4(W1[tid * 3], W1[tid * 3 + 1], W1[tid * 3 + 2], b1[tid]);
        st1[tid] = make_float2(s1t1[tid], s1t1[64 + tid]);
        st2[tid] = make_float2(s2t2[tid], s2t2[64 + tid]);
        b2l[tid] = b2[tid];
    }
    __syncthreads();
    const int s = blockIdx.x * 256 + tid;
    float r0 = rel[s * 3], r1 = rel[s * 3 + 1], r2 = rel[s * 3 + 2];
    float a[64];
#pragma unroll
    for (int c = 0; c < 64; ++c) {
        float4 w = W1l[c];
        float h = (w.x * r0 + w.y * r1 + w.z * r2) + w.w;
        float2 st = st1[c];
        a[c] = fmaxf(fmaf(st.x, h, st.y), 0.f);
    }
    float a2[64];
#pragma unroll
    for (int o = 0; o < 64; ++o) {
        float h2 = b2l[o];
#pragma unroll
        for (int c = 0; c < 64; c += 4) {
            float4 w = *(const float4*)&W2l[o * 64 + c];
            h2 = fmaf(w.x, a[c], h2);     h2 = fmaf(w.y, a[c + 1], h2);
            h2 = fmaf(w.z, a[c + 2], h2); h2 = fmaf(w.w, a[c + 3], h2);
        }
        float2 st = st2[o];
        a2[o] = fmaxf(fmaf(st.x, h2, st.y), 0.f);
    }
    const int kk = s & 15;
    const int n  = (s >> 4) & (NPTS - 1);
    const int bb = s >> 15;
#pragma unroll 1
    for (int o = 0; o < 64; ++o) {
        float h3 = b2l[o];
#pragma unroll
        for (int c = 0; c < 64; c += 4) {
            float4 w = *(const float4*)&W2l[o * 64 + c];
            h3 = fmaf(w.x, a2[c], h3);     h3 = fmaf(w.y, a2[c + 1], h3);
            h3 = fmaf(w.z, a2[c + 2], h3); h3 = fmaf(w.w, a2[c + 3], h3);
        }
        h3 = fmaxf(h3, __shfl_xor(h3, 1, 64));
        h3 = fmaxf(h3, __shfl_xor(h3, 2, 64));
        h3 = fmaxf(h3, __shfl_xor(h3, 4, 64));
        h3 = fmaxf(h3, __shfl_xor(h3, 8, 64));
        if (kk == 0) out[(size_t)bb * (CH * NPTS) + o * NPTS + n] = h3;
    }
}

extern "C" void kernel_launch(void* const* d_in, const int* in_sizes, int n_in,
                              void* d_out, int out_size, void* d_ws, size_t ws_size,
                              hipStream_t stream) {
    (void)in_sizes; (void)n_in; (void)out_size; (void)ws_size;
    const float* xyz   = (const float*)d_in[0];
    const float* W1    = (const float*)d_in[1];
    const float* b1    = (const float*)d_in[2];
    const float* W2    = (const float*)d_in[3];
    const float* b2    = (const float*)d_in[4];
    const float* gamma = (const float*)d_in[5];
    const float* beta  = (const float*)d_in[6];
    float* out = (float*)d_out;
    float* ws  = (float*)d_ws;

    float* rel   = ws + WS_REL;
    float* part1 = ws + WS_PART1;
    float* s1t1  = ws + WS_S1T1;
    float* part2 = ws + WS_PART2;
    float* s2t2  = ws + WS_S2T2;

    knn_rel_kernel<<<dim3(512), dim3(128), 0, stream>>>(xyz, rel, part1);
    fin1_kernel<<<dim3(1), dim3(64), 0, stream>>>(part1, W1, b1, gamma, beta, s1t1);
    stats2_kernel<<<dim3(256), dim3(256), 0, stream>>>(rel, W1, b1, W2, b2, s1t1, part2);
    fin2_kernel<<<dim3(1), dim3(64), 0, stream>>>(part2, gamma, beta, s2t2);
    out_kernel<<<dim3(1024), dim3(256), 0, stream>>>(rel, W1, b1, W2, b2, s1t1, s2t2, out);
}

// Round 2
// 431.015 us; speedup vs baseline: 3.2012x; 3.2012x over previous
//
#include <hip/hip_runtime.h>
#include <math.h>

#define BATCH 8
#define NPTS 2048
#define CH 64
#define KNB 16
#define M_SAMPLES (BATCH * NPTS * KNB)   // 262144

// ws layout (floats):
//   rel   : [0, 786432)          262144 * 3
//   s1t1  : [786432, 786560)     64 scale + 64 shift
//   s2t2  : [786560, 786688)
//   part1 : [786688, 823552)     4096 blocks * 9   (written K1, read K2)
//   part2 : aliases part1        256 blocks * 128  (written K3, read K4)
// total 3.294 MB (<= round-1's 3.30 MB)

#define WS_REL   0
#define WS_S1T1  786432
#define WS_S2T2  786560
#define WS_PART1 786688
#define WS_PART2 786688

// ---------------- K1: KNN (wave-cooperative 16x min-extract) + rel + BN1 moments ----
// grid 4096 (= 8 batches * 512 query-groups of 4), block 256 = 4 waves, 1 query/wave
__global__ __launch_bounds__(256) void knn_rel_kernel(const float* __restrict__ xyz,
                                                      float* __restrict__ rel,
                                                      float* __restrict__ part1) {
    __shared__ float4 pts[NPTS];          // 32 KB: x,y,z,|p|^2
    __shared__ float  red9[4][9];

    const int b     = blockIdx.x >> 9;
    const int qbase = (blockIdx.x & 511) * 4;
    const int tid   = threadIdx.x;
    const int wave  = tid >> 6, lane = tid & 63;

    const float* xb = xyz + (size_t)b * 3 * NPTS;
    for (int j = tid; j < NPTS; j += 256) {
        float x = xb[j], y = xb[NPTS + j], z = xb[2 * NPTS + j];
        pts[j] = make_float4(x, y, z, (x * x + y * y) + z * z);  // match np left-fold
    }
    __syncthreads();

    const int q = qbase + wave;
    const float4 pq = pts[q];

    // 32 candidates per lane, packed keys (d2_bits << 32) | j  -> unique, lex order
    unsigned long long key[32];
#pragma unroll
    for (int t = 0; t < 32; ++t) {
        const int j = t * 64 + lane;
        float4 pj = pts[j];
        float d2 = (pq.w + pj.w) - 2.0f * (pq.x * pj.x + pq.y * pj.y + pq.z * pj.z);
        d2 = fmaxf(d2, 0.0f);
        unsigned long long k = ((unsigned long long)__float_as_uint(d2) << 32) | (unsigned int)j;
        key[t] = (j == q) ? 0xFFFFFFFFFFFFFFFFull : k;
    }

    // 16 rounds: wave-wide min, then branchless invalidate
    unsigned long long win = 0;
#pragma unroll 1
    for (int it = 0; it < 16; ++it) {
        unsigned long long m = key[0];
#pragma unroll
        for (int t = 1; t < 32; ++t) m = (key[t] < m) ? key[t] : m;
#pragma unroll
        for (int d = 1; d < 64; d <<= 1) {
            unsigned long long o = __shfl_xor(m, d, 64);
            m = (o < m) ? o : m;
        }
#pragma unroll
        for (int t = 0; t < 32; ++t) key[t] = (key[t] == m) ? 0xFFFFFFFFFFFFFFFFull : key[t];
        if (lane == it) win = m;
    }

    // lanes 0..15 hold the 16 winners (set semantics; downstream is k-symmetric)
    float rr0 = 0.f, rr1 = 0.f, rr2 = 0.f;
    if (lane < 16) {
        const int j = (int)(win & 0xFFFFFFFFull);
        float4 pn = pts[j];
        rr0 = pn.x - pq.x; rr1 = pn.y - pq.y; rr2 = pn.z - pq.z;
        const size_t relbase = ((size_t)(b * NPTS + q)) * (KNB * 3);
        rel[relbase + lane * 3 + 0] = rr0;
        rel[relbase + lane * 3 + 1] = rr1;
        rel[relbase + lane * 3 + 2] = rr2;
    }

    // BN1 moment partials: 9 wave-reductions (lanes >=16 contribute zeros)
    float m0 = rr0, m1 = rr1, m2 = rr2;
    float m3 = rr0 * rr0, m4 = rr0 * rr1, m5 = rr0 * rr2;
    float m6 = rr1 * rr1, m7 = rr1 * rr2, m8 = rr2 * rr2;
#pragma unroll
    for (int d = 1; d < 64; d <<= 1) {
        m0 += __shfl_xor(m0, d, 64); m1 += __shfl_xor(m1, d, 64); m2 += __shfl_xor(m2, d, 64);
        m3 += __shfl_xor(m3, d, 64); m4 += __shfl_xor(m4, d, 64); m5 += __shfl_xor(m5, d, 64);
        m6 += __shfl_xor(m6, d, 64); m7 += __shfl_xor(m7, d, 64); m8 += __shfl_xor(m8, d, 64);
    }
    if (lane == 0) {
        red9[wave][0] = m0; red9[wave][1] = m1; red9[wave][2] = m2;
        red9[wave][3] = m3; red9[wave][4] = m4; red9[wave][5] = m5;
        red9[wave][6] = m6; red9[wave][7] = m7; red9[wave][8] = m8;
    }
    __syncthreads();
    if (tid < 9)
        part1[blockIdx.x * 9 + tid] =
            red9[0][tid] + red9[1][tid] + red9[2][tid] + red9[3][tid];
}

// ---------------- K2: finalize BN1 affine (closed form from rel moments) ----------------
__global__ __launch_bounds__(256) void fin1_kernel(const float* __restrict__ part1,
                            const float* __restrict__ W1, const float* __restrict__ b1,
                            const float* __restrict__ gamma, const float* __restrict__ beta,
                            float* __restrict__ s1t1) {
    __shared__ double red[9][256];
    __shared__ double sm[9];
    const int t = threadIdx.x;
    double s[9] = {0, 0, 0, 0, 0, 0, 0, 0, 0};
    for (int blk = t; blk < 4096; blk += 256)
#pragma unroll
        for (int v = 0; v < 9; ++v) s[v] += (double)part1[blk * 9 + v];
#pragma unroll
    for (int v = 0; v < 9; ++v) red[v][t] = s[v];
    __syncthreads();
    if (t < 9) {
        double x = 0.0;
        for (int i = 0; i < 256; ++i) x += red[t][i];
        sm[t] = x;
    }
    __syncthreads();
    if (t < 64) {
        const double Md = (double)M_SAMPLES;
        double mu0 = sm[0] / Md, mu1 = sm[1] / Md, mu2 = sm[2] / Md;
        double C00 = sm[3] / Md - mu0 * mu0;
        double C01 = sm[4] / Md - mu0 * mu1;
        double C02 = sm[5] / Md - mu0 * mu2;
        double C11 = sm[6] / Md - mu1 * mu1;
        double C12 = sm[7] / Md - mu1 * mu2;
        double C22 = sm[8] / Md - mu2 * mu2;
        double w0 = (double)W1[t * 3], w1 = (double)W1[t * 3 + 1], w2 = (double)W1[t * 3 + 2];
        double mean = w0 * mu0 + w1 * mu1 + w2 * mu2 + (double)b1[t];
        double var  = w0 * w0 * C00 + w1 * w1 * C11 + w2 * w2 * C22
                    + 2.0 * (w0 * w1 * C01 + w0 * w2 * C02 + w1 * w2 * C12);
        double sc = (double)gamma[t] / sqrt(var + 1e-5);
        s1t1[t]      = (float)sc;
        s1t1[64 + t] = (float)((double)beta[t] - mean * sc);
    }
}

// ---------------- K3: BN2 statistics (sum, sumsq of h2 per channel) ----------------
__global__ __launch_bounds__(256) void stats2_kernel(const float* __restrict__ rel,
        const float* __restrict__ W1, const float* __restrict__ b1,
        const float* __restrict__ W2, const float* __restrict__ b2,
        const float* __restrict__ s1t1, float* __restrict__ part2) {
    __shared__ float  W2l[64 * 64];
    __shared__ float4 W1l[64];
    __shared__ float2 st1[64];
    __shared__ float  b2l[64];
    __shared__ float  acc[4][128];
    const int tid = threadIdx.x;
    for (int i = tid; i < 4096; i += 256) W2l[i] = W2[i];
    if (tid < 64) {
        W1l[tid] = make_float4(W1[tid * 3], W1[tid * 3 + 1], W1[tid * 3 + 2], b1[tid]);
        st1[tid] = make_float2(s1t1[tid], s1t1[64 + tid]);
        b2l[tid] = b2[tid];
    }
    for (int i = tid; i < 512; i += 256) ((float*)acc)[i] = 0.f;
    __syncthreads();
    const int wave = tid >> 6, lane = tid & 63;
    for (int it = 0; it < 4; ++it) {
        const int s = (blockIdx.x * 4 + it) * 256 + tid;
        float r0 = rel[s * 3], r1 = rel[s * 3 + 1], r2 = rel[s * 3 + 2];
        float a[64];
#pragma unroll
        for (int c = 0; c < 64; ++c) {
            float4 w = W1l[c];
            float h = (w.x * r0 + w.y * r1 + w.z * r2) + w.w;
            float2 st = st1[c];
            a[c] = fmaxf(fmaf(st.x, h, st.y), 0.f);
        }
#pragma unroll 1
        for (int o = 0; o < 64; ++o) {
            float h2 = b2l[o];
#pragma unroll
            for (int c = 0; c < 64; c += 4) {
                float4 w = *(const float4*)&W2l[o * 64 + c];
                h2 = fmaf(w.x, a[c], h2);     h2 = fmaf(w.y, a[c + 1], h2);
                h2 = fmaf(w.z, a[c + 2], h2); h2 = fmaf(w.w, a[c + 3], h2);
            }
            float sq = h2 * h2;
#pragma unroll
            for (int d = 1; d < 64; d <<= 1) {
                h2 += __shfl_xor(h2, d, 64);
                sq += __shfl_xor(sq, d, 64);
            }
            if (lane == 0) { acc[wave][o * 2] += h2; acc[wave][o * 2 + 1] += sq; }
        }
    }
    __syncthreads();
    if (tid < 128)
        part2[blockIdx.x * 128 + tid] = acc[0][tid] + acc[1][tid] + acc[2][tid] + acc[3][tid];
}

// ---------------- K4: finalize BN2 affine ----------------
__global__ void fin2_kernel(const float* __restrict__ part2,
                            const float* __restrict__ gamma, const float* __restrict__ beta,
                            float* __restrict__ s2t2) {
    int o = threadIdx.x;
    double s = 0.0, sq = 0.0;
    for (int i = 0; i < 256; ++i) {
        s  += (double)part2[i * 128 + o * 2];
        sq += (double)part2[i * 128 + o * 2 + 1];
    }
    const double Md = (double)M_SAMPLES;
    double mean = s / Md;
    double var  = sq / Md - mean * mean;
    double sc = (double)gamma[o] / sqrt(var + 1e-5);
    s2t2[o]      = (float)sc;
    s2t2[64 + o] = (float)((double)beta[o] - mean * sc);
}

// ---------------- K5: full chain + max over k, write [B,C,N] ----------------
__global__ __launch_bounds__(256) void out_kernel(const float* __restrict__ rel,
        const float* __restrict__ W1, const float* __restrict__ b1,
        const float* __restrict__ W2, const float* __restrict__ b2,
        const float* __restrict__ s1t1, const float* __restrict__ s2t2,
        float* __restrict__ out) {
    __shared__ float  W2l[64 * 64];
    __shared__ float4 W1l[64];
    __shared__ float2 st1[64];
    __shared__ float2 st2[64];
    __shared__ float  b2l[64];
    const int tid = threadIdx.x;
    for (int i = tid; i < 4096; i += 256) W2l[i] = W2[i];
    if (tid < 64) {
        W1l[tid] = make_float4(W1[tid * 3], W1[tid * 3 + 1], W1[tid * 3 + 2], b1[tid]);
        st1[tid] = make_float2(s1t1[tid], s1t1[64 + tid]);
        st2[tid] = make_float2(s2t2[tid], s2t2[64 + tid]);
        b2l[tid] = b2[tid];
    }
    __syncthreads();
    const int s = blockIdx.x * 256 + tid;
    float r0 = rel[s * 3], r1 = rel[s * 3 + 1], r2 = rel[s * 3 + 2];
    float a[64];
#pragma unroll
    for (int c = 0; c < 64; ++c) {
        float4 w = W1l[c];
        float h = (w.x * r0 + w.y * r1 + w.z * r2) + w.w;
        float2 st = st1[c];
        a[c] = fmaxf(fmaf(st.x, h, st.y), 0.f);
    }
    float a2[64];
#pragma unroll
    for (int o = 0; o < 64; ++o) {
        float h2 = b2l[o];
#pragma unroll
        for (int c = 0; c < 64; c += 4) {
            float4 w = *(const float4*)&W2l[o * 64 + c];
            h2 = fmaf(w.x, a[c], h2);     h2 = fmaf(w.y, a[c + 1], h2);
            h2 = fmaf(w.z, a[c + 2], h2); h2 = fmaf(w.w, a[c + 3], h2);
        }
        float2 st = st2[o];
        a2[o] = fmaxf(fmaf(st.x, h2, st.y), 0.f);
    }
    const int kk = s & 15;
    const int n  = (s >> 4) & (NPTS - 1);
    const int bb = s >> 15;
#pragma unroll 1
    for (int o = 0; o < 64; ++o) {
        float h3 = b2l[o];
#pragma unroll
        for (int c = 0; c < 64; c += 4) {
            float4 w = *(const float4*)&W2l[o * 64 + c];
            h3 = fmaf(w.x, a2[c], h3);     h3 = fmaf(w.y, a2[c + 1], h3);
            h3 = fmaf(w.z, a2[c + 2], h3); h3 = fmaf(w.w, a2[c + 3], h3);
        }
        h3 = fmaxf(h3, __shfl_xor(h3, 1, 64));
        h3 = fmaxf(h3, __shfl_xor(h3, 2, 64));
        h3 = fmaxf(h3, __shfl_xor(h3, 4, 64));
        h3 = fmaxf(h3, __shfl_xor(h3, 8, 64));
        if (kk == 0) out[(size_t)bb * (CH * NPTS) + o * NPTS + n] = h3;
    }
}

extern "C" void kernel_launch(void* const* d_in, const int* in_sizes, int n_in,
                              void* d_out, int out_size, void* d_ws, size_t ws_size,
                              hipStream_t stream) {
    (void)in_sizes; (void)n_in; (void)out_size; (void)ws_size;
    const float* xyz   = (const float*)d_in[0];
    const float* W1    = (const float*)d_in[1];
    const float* b1    = (const float*)d_in[2];
    const float* W2    = (const float*)d_in[3];
    const float* b2    = (const float*)d_in[4];
    const float* gamma = (const float*)d_in[5];
    const float* beta  = (const float*)d_in[6];
    float* out = (float*)d_out;
    float* ws  = (float*)d_ws;

    float* rel   = ws + WS_REL;
    float* s1t1  = ws + WS_S1T1;
    float* s2t2  = ws + WS_S2T2;
    float* part1 = ws + WS_PART1;
    float* part2 = ws + WS_PART2;

    knn_rel_kernel<<<dim3(4096), dim3(256), 0, stream>>>(xyz, rel, part1);
    fin1_kernel<<<dim3(1), dim3(256), 0, stream>>>(part1, W1, b1, gamma, beta, s1t1);
    stats2_kernel<<<dim3(256), dim3(256), 0, stream>>>(rel, W1, b1, W2, b2, s1t1, part2);
    fin2_kernel<<<dim3(1), dim3(64), 0, stream>>>(part2, gamma, beta, s2t2);
    out_kernel<<<dim3(1024), dim3(256), 0, stream>>>(rel, W1, b1, W2, b2, s1t1, s2t2, out);
}

// Round 7
// 334.280 us; speedup vs baseline: 4.1275x; 1.2894x over previous
//
#include <hip/hip_runtime.h>
#include <math.h>

#define BATCH 8
#define NPTS 2048
#define CH 64
#define KNB 16
#define M_SAMPLES (BATCH * NPTS * KNB)   // 262144

// ws layout (float offsets) — peak 823552 floats = 3.29 MB:
//   rel   : [0, 786432)          262144 * 3 f32
//   s1t1  : [786432, 786560)
//   s2t2  : [786560, 786688)
//   part1 : [786688, 823552)     4096 blocks * 9   (knn -> fin1; dead after fin1)
//   part2 : [786688, 819456)     256 blocks * 128  (aliases part1; stats2 -> fin2)
#define WS_REL   0
#define WS_S1T1  786432
#define WS_S2T2  786560
#define WS_PART1 786688
#define WS_PART2 786688

#define SURV_CAP 192
// ABSOLUTE d2 slack for the survivor filter. Pass-1/pass-2 are separately
// contracted loops; cancellation in (sq_q+sq_j)-2*dot makes their difference
// up to ~1.5e-5 ABSOLUTE (intermediates ~6-60), which can be >>1000 ulps of a
// small d2 — ulp-space slack (round 6) was structurally wrong. 1e-4 covers the
// noise with 6x margin and is << typical rank-16 neighbor gaps (~1e-3).
#define D2_EPS 1e-4f

__device__ __forceinline__ unsigned long long u64min(unsigned long long a, unsigned long long b) { return a < b ? a : b; }
__device__ __forceinline__ unsigned long long u64max(unsigned long long a, unsigned long long b) { return a > b ? a : b; }

// full 64-lane bitonic sort, ascending by lane; output is runtime-verified
__device__ __forceinline__ unsigned long long bitonic64(unsigned long long v, int lane) {
#pragma unroll
    for (int k = 2; k <= 64; k <<= 1)
#pragma unroll
        for (int d = k >> 1; d >= 1; d >>= 1) {
            unsigned long long o = __shfl_xor(v, d, 64);
            bool keepmin = (((lane & d) == 0) == ((lane & k) == 0));
            v = keepmin ? u64min(v, o) : u64max(v, o);
        }
    return v;
}

// packed (d2_bits, index) key; self -> all-ones (d2 bits = NaN)
__device__ __forceinline__ unsigned long long cand_key(const float4 pq, const float4 pj, int j, int q) {
    float dot = pq.x * pj.x + pq.y * pj.y + pq.z * pj.z;
    float d2 = fmaxf((pq.w + pj.w) - 2.0f * dot, 0.0f);
    unsigned long long key = ((unsigned long long)__float_as_uint(d2) << 32) | (unsigned int)j;
    return (j == q) ? ~0ull : key;
}

// ---------------- K1: KNN, guarded threshold fast path + exact fallback ----------------
// grid 4096 (8 batches * 512 groups of 4), block 256 = 4 waves, 1 query/wave
__global__ __launch_bounds__(256) void knn_rel_kernel(const float* __restrict__ xyz,
                                                      float* __restrict__ rel,
                                                      float* __restrict__ part1) {
    __shared__ float4 pts[NPTS];                       // 32 KB
    __shared__ unsigned long long surv[4][SURV_CAP];   // 6 KB
    __shared__ unsigned int wavecnt[4];
    __shared__ float red9[4][9];

    const int b     = blockIdx.x >> 9;
    const int qbase = (blockIdx.x & 511) * 4;
    const int tid   = threadIdx.x;
    const int wave  = tid >> 6, lane = tid & 63;

    const float* xb = xyz + (size_t)b * 3 * NPTS;
    for (int j = tid; j < NPTS; j += 256) {
        float x = xb[j], y = xb[NPTS + j], z = xb[2 * NPTS + j];
        pts[j] = make_float4(x, y, z, (x * x + y * y) + z * z);
    }
    __syncthreads();

    const int q = qbase + wave;
    const float4 pq = pts[q];

    // pass 1: per-lane min key over this lane's 32 candidates
    unsigned long long lm = ~0ull;
#pragma unroll
    for (int t = 0; t < 32; ++t) {
        const int j = t * 64 + lane;
        lm = u64min(lm, cand_key(pq, pts[j], j, q));
    }
    // T = 16th smallest lane-min (>= true 16th distance). Even a garbage T is
    // safe: it only selects fast path vs fallback.
    unsigned long long sorted = bitonic64(lm, lane);
    const float Td2 = __uint_as_float((unsigned int)(__shfl(sorted, 15, 64) >> 32)) + D2_EPS;

    // pass 2: append survivors (d2 <= Td2) to per-wave LDS. Self has NaN d2
    // bits -> comparison false -> auto-excluded.
    if (lane == 0) wavecnt[wave] = 0u;
#pragma unroll
    for (int t = 0; t < 32; ++t) {
        const int j = t * 64 + lane;
        unsigned long long key = cand_key(pq, pts[j], j, q);
        float d2 = __uint_as_float((unsigned int)(key >> 32));
        if (d2 <= Td2) {
            unsigned int pos = atomicAdd(&wavecnt[wave], 1u);
            if (pos < SURV_CAP) surv[wave][pos] = key;
        }
    }
    const unsigned int total = wavecnt[wave];

    // pass 3: top-16. Fast path requires 16..64 survivors AND verified-sorted
    // output (compare-exchange preserves the multiset, so sorted => correct).
    unsigned long long wkey = ~0ull;
    bool ok = false;
    if (total >= 16u && total <= 64u) {
        unsigned long long s0 = (lane < (int)total) ? surv[wave][lane] : ~0ull;
        wkey = bitonic64(s0, lane);
        unsigned long long nxt = __shfl_down(wkey, 1, 64);
        ok = __all((lane == 63) || (wkey <= nxt)) != 0;
    }
    if (!ok) {
        // exact chained extract-min; single pinned loop instantiation is
        // self-consistent (bit-identical recompute across rounds).
        unsigned long long last = 0ull; bool first = true;
#pragma unroll 1
        for (int r = 0; r < 16; ++r) {
            unsigned long long m = ~0ull;
#pragma unroll
            for (int t = 0; t < 32; ++t) {
                const int j = t * 64 + lane;
                unsigned long long key = cand_key(pq, pts[j], j, q);
                if (first || key > last) m = u64min(m, key);
            }
#pragma unroll
            for (int d = 1; d < 64; d <<= 1) m = u64min(m, __shfl_xor(m, d, 64));
            if (lane == r) wkey = m;
            last = m; first = false;
        }
    }

    // winners: lanes 0..15 hold top-16. write rel + BN1 moment partials.
    float rr0 = 0.f, rr1 = 0.f, rr2 = 0.f;
    if (lane < 16) {
        const int j = ((int)(unsigned int)wkey) & (NPTS - 1);   // OOB-proof
        float4 pn = pts[j];
        rr0 = pn.x - pq.x; rr1 = pn.y - pq.y; rr2 = pn.z - pq.z;
        const size_t relbase = ((size_t)(b * NPTS + q)) * (KNB * 3);
        rel[relbase + lane * 3 + 0] = rr0;
        rel[relbase + lane * 3 + 1] = rr1;
        rel[relbase + lane * 3 + 2] = rr2;
    }
    float m0 = rr0, m1 = rr1, m2 = rr2;
    float m3 = rr0 * rr0, m4 = rr0 * rr1, m5 = rr0 * rr2;
    float m6 = rr1 * rr1, m7 = rr1 * rr2, m8 = rr2 * rr2;
#pragma unroll
    for (int d = 1; d < 64; d <<= 1) {
        m0 += __shfl_xor(m0, d, 64); m1 += __shfl_xor(m1, d, 64); m2 += __shfl_xor(m2, d, 64);
        m3 += __shfl_xor(m3, d, 64); m4 += __shfl_xor(m4, d, 64); m5 += __shfl_xor(m5, d, 64);
        m6 += __shfl_xor(m6, d, 64); m7 += __shfl_xor(m7, d, 64); m8 += __shfl_xor(m8, d, 64);
    }
    if (lane == 0) {
        red9[wave][0] = m0; red9[wave][1] = m1; red9[wave][2] = m2;
        red9[wave][3] = m3; red9[wave][4] = m4; red9[wave][5] = m5;
        red9[wave][6] = m6; red9[wave][7] = m7; red9[wave][8] = m8;
    }
    __syncthreads();
    if (tid < 9)
        part1[blockIdx.x * 9 + tid] =
            red9[0][tid] + red9[1][tid] + red9[2][tid] + red9[3][tid];
}

// ---------------- K2: finalize BN1 affine ----------------
__global__ __launch_bounds__(256) void fin1_kernel(const float* __restrict__ part1,
                            const float* __restrict__ W1, const float* __restrict__ b1,
                            const float* __restrict__ gamma, const float* __restrict__ beta,
                            float* __restrict__ s1t1) {
    __shared__ double red[9][256];
    __shared__ double sm[9];
    const int t = threadIdx.x;
    double s[9] = {0, 0, 0, 0, 0, 0, 0, 0, 0};
    for (int blk = t; blk < 4096; blk += 256)
#pragma unroll
        for (int v = 0; v < 9; ++v) s[v] += (double)part1[blk * 9 + v];
#pragma unroll
    for (int v = 0; v < 9; ++v) red[v][t] = s[v];
    __syncthreads();
    if (t < 9) {
        double x = 0.0;
        for (int i = 0; i < 256; ++i) x += red[t][i];
        sm[t] = x;
    }
    __syncthreads();
    if (t < 64) {
        const double Md = (double)M_SAMPLES;
        double mu0 = sm[0] / Md, mu1 = sm[1] / Md, mu2 = sm[2] / Md;
        double C00 = sm[3] / Md - mu0 * mu0;
        double C01 = sm[4] / Md - mu0 * mu1;
        double C02 = sm[5] / Md - mu0 * mu2;
        double C11 = sm[6] / Md - mu1 * mu1;
        double C12 = sm[7] / Md - mu1 * mu2;
        double C22 = sm[8] / Md - mu2 * mu2;
        double w0 = (double)W1[t * 3], w1 = (double)W1[t * 3 + 1], w2 = (double)W1[t * 3 + 2];
        double mean = w0 * mu0 + w1 * mu1 + w2 * mu2 + (double)b1[t];
        double var  = w0 * w0 * C00 + w1 * w1 * C11 + w2 * w2 * C22
                    + 2.0 * (w0 * w1 * C01 + w0 * w2 * C02 + w1 * w2 * C12);
        double sc = (double)gamma[t] / sqrt(var + 1e-5);
        s1t1[t]      = (float)sc;
        s1t1[64 + t] = (float)((double)beta[t] - mean * sc);
    }
}

// ---------------- K3: BN2 statistics (R2-verbatim, known-passing) ----------------
__global__ __launch_bounds__(256) void stats2_kernel(const float* __restrict__ rel,
        const float* __restrict__ W1, const float* __restrict__ b1,
        const float* __restrict__ W2, const float* __restrict__ b2,
        const float* __restrict__ s1t1, float* __restrict__ part2) {
    __shared__ float  W2l[64 * 64];
    __shared__ float4 W1l[64];
    __shared__ float2 st1[64];
    __shared__ float  b2l[64];
    __shared__ float  acc[4][128];
    const int tid = threadIdx.x;
    for (int i = tid; i < 4096; i += 256) W2l[i] = W2[i];
    if (tid < 64) {
        W1l[tid] = make_float4(W1[tid * 3], W1[tid * 3 + 1], W1[tid * 3 + 2], b1[tid]);
        st1[tid] = make_float2(s1t1[tid], s1t1[64 + tid]);
        b2l[tid] = b2[tid];
    }
    for (int i = tid; i < 512; i += 256) ((float*)acc)[i] = 0.f;
    __syncthreads();
    const int wave = tid >> 6, lane = tid & 63;
    for (int it = 0; it < 4; ++it) {
        const int s = (blockIdx.x * 4 + it) * 256 + tid;
        float r0 = rel[s * 3], r1 = rel[s * 3 + 1], r2 = rel[s * 3 + 2];
        float a[64];
#pragma unroll
        for (int c = 0; c < 64; ++c) {
            float4 w = W1l[c];
            float h = (w.x * r0 + w.y * r1 + w.z * r2) + w.w;
            float2 st = st1[c];
            a[c] = fmaxf(fmaf(st.x, h, st.y), 0.f);
        }
#pragma unroll 1
        for (int o = 0; o < 64; ++o) {
            float h2 = b2l[o];
#pragma unroll
            for (int c = 0; c < 64; c += 4) {
                float4 w = *(const float4*)&W2l[o * 64 + c];
                h2 = fmaf(w.x, a[c], h2);     h2 = fmaf(w.y, a[c + 1], h2);
                h2 = fmaf(w.z, a[c + 2], h2); h2 = fmaf(w.w, a[c + 3], h2);
            }
            float sq = h2 * h2;
#pragma unroll
            for (int d = 1; d < 64; d <<= 1) {
                h2 += __shfl_xor(h2, d, 64);
                sq += __shfl_xor(sq, d, 64);
            }
            if (lane == 0) { acc[wave][o * 2] += h2; acc[wave][o * 2 + 1] += sq; }
        }
    }
    __syncthreads();
    if (tid < 128)
        part2[blockIdx.x * 128 + tid] = acc[0][tid] + acc[1][tid] + acc[2][tid] + acc[3][tid];
}

// ---------------- K4: finalize BN2 affine (R2-verbatim, known-passing) ----------------
__global__ void fin2_kernel(const float* __restrict__ part2,
                            const float* __restrict__ gamma, const float* __restrict__ beta,
                            float* __restrict__ s2t2) {
    int o = threadIdx.x;
    double s = 0.0, sq = 0.0;
    for (int i = 0; i < 256; ++i) {
        s  += (double)part2[i * 128 + o * 2];
        sq += (double)part2[i * 128 + o * 2 + 1];
    }
    const double Md = (double)M_SAMPLES;
    double mean = s / Md;
    double var  = sq / Md - mean * mean;
    double sc = (double)gamma[o] / sqrt(var + 1e-5);
    s2t2[o]      = (float)sc;
    s2t2[64 + o] = (float)((double)beta[o] - mean * sc);
}

// ---------------- K5: full chain + max over k, write [B,C,N] (R2-verbatim) -------------
__global__ __launch_bounds__(256) void out_kernel(const float* __restrict__ rel,
        const float* __restrict__ W1, const float* __restrict__ b1,
        const float* __restrict__ W2, const float* __restrict__ b2,
        const float* __restrict__ s1t1, const float* __restrict__ s2t2,
        float* __restrict__ out) {
    __shared__ float  W2l[64 * 64];
    __shared__ float4 W1l[64];
    __shared__ float2 st1[64];
    __shared__ float2 st2[64];
    __shared__ float  b2l[64];
    const int tid = threadIdx.x;
    for (int i = tid; i < 4096; i += 256) W2l[i] = W2[i];
    if (tid < 64) {
        W1l[tid] = make_float4(W1[tid * 3], W1[tid * 3 + 1], W1[tid * 3 + 2], b1[tid]);
        st1[tid] = make_float2(s1t1[tid], s1t1[64 + tid]);
        st2[tid] = make_float2(s2t2[tid], s2t2[64 + tid]);
        b2l[tid] = b2[tid];
    }
    __syncthreads();
    const int s = blockIdx.x * 256 + tid;
    float r0 = rel[s * 3], r1 = rel[s * 3 + 1], r2 = rel[s * 3 + 2];
    float a[64];
#pragma unroll
    for (int c = 0; c < 64; ++c) {
        float4 w = W1l[c];
        float h = (w.x * r0 + w.y * r1 + w.z * r2) + w.w;
        float2 st = st1[c];
        a[c] = fmaxf(fmaf(st.x, h, st.y), 0.f);
    }
    float a2[64];
#pragma unroll
    for (int o = 0; o < 64; ++o) {
        float h2 = b2l[o];
#pragma unroll
        for (int c = 0; c < 64; c += 4) {
            float4 w = *(const float4*)&W2l[o * 64 + c];
            h2 = fmaf(w.x, a[c], h2);     h2 = fmaf(w.y, a[c + 1], h2);
            h2 = fmaf(w.z, a[c + 2], h2); h2 = fmaf(w.w, a[c + 3], h2);
        }
        float2 st = st2[o];
        a2[o] = fmaxf(fmaf(st.x, h2, st.y), 0.f);
    }
    const int kk = s & 15;
    const int n  = (s >> 4) & (NPTS - 1);
    const int bb = s >> 15;
#pragma unroll 1
    for (int o = 0; o < 64; ++o) {
        float h3 = b2l[o];
#pragma unroll
        for (int c = 0; c < 64; c += 4) {
            float4 w = *(const float4*)&W2l[o * 64 + c];
            h3 = fmaf(w.x, a2[c], h3);     h3 = fmaf(w.y, a2[c + 1], h3);
            h3 = fmaf(w.z, a2[c + 2], h3); h3 = fmaf(w.w, a2[c + 3], h3);
        }
        h3 = fmaxf(h3, __shfl_xor(h3, 1, 64));
        h3 = fmaxf(h3, __shfl_xor(h3, 2, 64));
        h3 = fmaxf(h3, __shfl_xor(h3, 4, 64));
        h3 = fmaxf(h3, __shfl_xor(h3, 8, 64));
        if (kk == 0) out[(size_t)bb * (CH * NPTS) + o * NPTS + n] = h3;
    }
}

extern "C" void kernel_launch(void* const* d_in, const int* in_sizes, int n_in,
                              void* d_out, int out_size, void* d_ws, size_t ws_size,
                              hipStream_t stream) {
    (void)in_sizes; (void)n_in; (void)out_size; (void)ws_size;
    const float* xyz   = (const float*)d_in[0];
    const float* W1    = (const float*)d_in[1];
    const float* b1    = (const float*)d_in[2];
    const float* W2    = (const float*)d_in[3];
    const float* b2    = (const float*)d_in[4];
    const float* gamma = (const float*)d_in[5];
    const float* beta  = (const float*)d_in[6];
    float* out = (float*)d_out;
    float* ws  = (float*)d_ws;

    float* rel   = ws + WS_REL;
    float* s1t1  = ws + WS_S1T1;
    float* s2t2  = ws + WS_S2T2;
    float* part1 = ws + WS_PART1;
    float* part2 = ws + WS_PART2;   // aliases part1: fin1 consumes part1 before stats2 writes

    knn_rel_kernel<<<dim3(4096), dim3(256), 0, stream>>>(xyz, rel, part1);
    fin1_kernel<<<dim3(1), dim3(256), 0, stream>>>(part1, W1, b1, gamma, beta, s1t1);
    stats2_kernel<<<dim3(256), dim3(256), 0, stream>>>(rel, W1, b1, W2, b2, s1t1, part2);
    fin2_kernel<<<dim3(1), dim3(64), 0, stream>>>(part2, gamma, beta, s2t2);
    out_kernel<<<dim3(1024), dim3(256), 0, stream>>>(rel, W1, b1, W2, b2, s1t1, s2t2, out);
}

// Round 8
// 292.785 us; speedup vs baseline: 4.7125x; 1.1417x over previous
//
#include <hip/hip_runtime.h>
#include <math.h>

#define BATCH 8
#define NPTS 2048
#define CH 64
#define KNB 16
#define M_SAMPLES (BATCH * NPTS * KNB)   // 262144
#define FIXSCALE 1048576.0               // 2^20 fixed-point for deterministic atomics

// ws layout (float offsets) — peak 823552 floats = 3.29 MB (unchanged):
//   rel   : [0, 786432)          262144 * 3 f32
//   s1t1  : [786432, 786560)
//   s2t2  : [786560, 786688)
//   part1 : [786688, 823552)     4096 blocks * 9  (knn -> fin1; dead after fin1)
//   Gfix  : [786688, 795008)     4160 u64, aliases part1 (zeroed in fin1 AFTER
//                                part1 is consumed; gram accumulates; fin2G reads)
#define WS_REL   0
#define WS_S1T1  786432
#define WS_S2T2  786560
#define WS_PART1 786688
#define WS_GFIX  786688

#define SURV_CAP 192
// ABSOLUTE d2 slack (see R7): covers cross-loop fp-contraction noise (~1.5e-5)
// with 6x margin; garbage T only routes to the exact fallback.
#define D2_EPS 1e-4f

__device__ __forceinline__ unsigned long long u64min(unsigned long long a, unsigned long long b) { return a < b ? a : b; }
__device__ __forceinline__ unsigned long long u64max(unsigned long long a, unsigned long long b) { return a > b ? a : b; }

__device__ __forceinline__ unsigned long long bitonic64(unsigned long long v, int lane) {
#pragma unroll
    for (int k = 2; k <= 64; k <<= 1)
#pragma unroll
        for (int d = k >> 1; d >= 1; d >>= 1) {
            unsigned long long o = __shfl_xor(v, d, 64);
            bool keepmin = (((lane & d) == 0) == ((lane & k) == 0));
            v = keepmin ? u64min(v, o) : u64max(v, o);
        }
    return v;
}

__device__ __forceinline__ unsigned long long cand_key(const float4 pq, const float4 pj, int j, int q) {
    float dot = pq.x * pj.x + pq.y * pj.y + pq.z * pj.z;
    float d2 = fmaxf((pq.w + pj.w) - 2.0f * dot, 0.0f);
    unsigned long long key = ((unsigned long long)__float_as_uint(d2) << 32) | (unsigned int)j;
    return (j == q) ? ~0ull : key;
}

// ---------------- K1: KNN (R7-verbatim, proven) ----------------
__global__ __launch_bounds__(256) void knn_rel_kernel(const float* __restrict__ xyz,
                                                      float* __restrict__ rel,
                                                      float* __restrict__ part1) {
    __shared__ float4 pts[NPTS];
    __shared__ unsigned long long surv[4][SURV_CAP];
    __shared__ unsigned int wavecnt[4];
    __shared__ float red9[4][9];

    const int b     = blockIdx.x >> 9;
    const int qbase = (blockIdx.x & 511) * 4;
    const int tid   = threadIdx.x;
    const int wave  = tid >> 6, lane = tid & 63;

    const float* xb = xyz + (size_t)b * 3 * NPTS;
    for (int j = tid; j < NPTS; j += 256) {
        float x = xb[j], y = xb[NPTS + j], z = xb[2 * NPTS + j];
        pts[j] = make_float4(x, y, z, (x * x + y * y) + z * z);
    }
    __syncthreads();

    const int q = qbase + wave;
    const float4 pq = pts[q];

    unsigned long long lm = ~0ull;
#pragma unroll
    for (int t = 0; t < 32; ++t) {
        const int j = t * 64 + lane;
        lm = u64min(lm, cand_key(pq, pts[j], j, q));
    }
    unsigned long long sorted = bitonic64(lm, lane);
    const float Td2 = __uint_as_float((unsigned int)(__shfl(sorted, 15, 64) >> 32)) + D2_EPS;

    if (lane == 0) wavecnt[wave] = 0u;
#pragma unroll
    for (int t = 0; t < 32; ++t) {
        const int j = t * 64 + lane;
        unsigned long long key = cand_key(pq, pts[j], j, q);
        float d2 = __uint_as_float((unsigned int)(key >> 32));
        if (d2 <= Td2) {
            unsigned int pos = atomicAdd(&wavecnt[wave], 1u);
            if (pos < SURV_CAP) surv[wave][pos] = key;
        }
    }
    const unsigned int total = wavecnt[wave];

    unsigned long long wkey = ~0ull;
    bool ok = false;
    if (total >= 16u && total <= 64u) {
        unsigned long long s0 = (lane < (int)total) ? surv[wave][lane] : ~0ull;
        wkey = bitonic64(s0, lane);
        unsigned long long nxt = __shfl_down(wkey, 1, 64);
        ok = __all((lane == 63) || (wkey <= nxt)) != 0;
    }
    if (!ok) {
        unsigned long long last = 0ull; bool first = true;
#pragma unroll 1
        for (int r = 0; r < 16; ++r) {
            unsigned long long m = ~0ull;
#pragma unroll
            for (int t = 0; t < 32; ++t) {
                const int j = t * 64 + lane;
                unsigned long long key = cand_key(pq, pts[j], j, q);
                if (first || key > last) m = u64min(m, key);
            }
#pragma unroll
            for (int d = 1; d < 64; d <<= 1) m = u64min(m, __shfl_xor(m, d, 64));
            if (lane == r) wkey = m;
            last = m; first = false;
        }
    }

    float rr0 = 0.f, rr1 = 0.f, rr2 = 0.f;
    if (lane < 16) {
        const int j = ((int)(unsigned int)wkey) & (NPTS - 1);
        float4 pn = pts[j];
        rr0 = pn.x - pq.x; rr1 = pn.y - pq.y; rr2 = pn.z - pq.z;
        const size_t relbase = ((size_t)(b * NPTS + q)) * (KNB * 3);
        rel[relbase + lane * 3 + 0] = rr0;
        rel[relbase + lane * 3 + 1] = rr1;
        rel[relbase + lane * 3 + 2] = rr2;
    }
    float m0 = rr0, m1 = rr1, m2 = rr2;
    float m3 = rr0 * rr0, m4 = rr0 * rr1, m5 = rr0 * rr2;
    float m6 = rr1 * rr1, m7 = rr1 * rr2, m8 = rr2 * rr2;
#pragma unroll
    for (int d = 1; d < 64; d <<= 1) {
        m0 += __shfl_xor(m0, d, 64); m1 += __shfl_xor(m1, d, 64); m2 += __shfl_xor(m2, d, 64);
        m3 += __shfl_xor(m3, d, 64); m4 += __shfl_xor(m4, d, 64); m5 += __shfl_xor(m5, d, 64);
        m6 += __shfl_xor(m6, d, 64); m7 += __shfl_xor(m7, d, 64); m8 += __shfl_xor(m8, d, 64);
    }
    if (lane == 0) {
        red9[wave][0] = m0; red9[wave][1] = m1; red9[wave][2] = m2;
        red9[wave][3] = m3; red9[wave][4] = m4; red9[wave][5] = m5;
        red9[wave][6] = m6; red9[wave][7] = m7; red9[wave][8] = m8;
    }
    __syncthreads();
    if (tid < 9)
        part1[blockIdx.x * 9 + tid] =
            red9[0][tid] + red9[1][tid] + red9[2][tid] + red9[3][tid];
}

// ---------------- K2: finalize BN1 affine + zero Gfix (part1 is consumed here) --------
__global__ __launch_bounds__(256) void fin1_kernel(const float* __restrict__ part1,
                            const float* __restrict__ W1, const float* __restrict__ b1,
                            const float* __restrict__ gamma, const float* __restrict__ beta,
                            float* __restrict__ s1t1, unsigned long long* __restrict__ Gfix) {
    __shared__ double red[9][256];
    __shared__ double sm[9];
    const int t = threadIdx.x;
    double s[9] = {0, 0, 0, 0, 0, 0, 0, 0, 0};
    for (int blk = t; blk < 4096; blk += 256)
#pragma unroll
        for (int v = 0; v < 9; ++v) s[v] += (double)part1[blk * 9 + v];
#pragma unroll
    for (int v = 0; v < 9; ++v) red[v][t] = s[v];
    __syncthreads();
    // part1 fully consumed -> safe to zero Gfix (aliases part1's memory).
    // Re-zeroed every launch => graph replays stay deterministic.
    for (int i = t; i < 4160; i += 256) Gfix[i] = 0ull;
    if (t < 9) {
        double x = 0.0;
        for (int i = 0; i < 256; ++i) x += red[t][i];
        sm[t] = x;
    }
    __syncthreads();
    if (t < 64) {
        const double Md = (double)M_SAMPLES;
        double mu0 = sm[0] / Md, mu1 = sm[1] / Md, mu2 = sm[2] / Md;
        double C00 = sm[3] / Md - mu0 * mu0;
        double C01 = sm[4] / Md - mu0 * mu1;
        double C02 = sm[5] / Md - mu0 * mu2;
        double C11 = sm[6] / Md - mu1 * mu1;
        double C12 = sm[7] / Md - mu1 * mu2;
        double C22 = sm[8] / Md - mu2 * mu2;
        double w0 = (double)W1[t * 3], w1 = (double)W1[t * 3 + 1], w2 = (double)W1[t * 3 + 2];
        double mean = w0 * mu0 + w1 * mu1 + w2 * mu2 + (double)b1[t];
        double var  = w0 * w0 * C00 + w1 * w1 * C11 + w2 * w2 * C22
                    + 2.0 * (w0 * w1 * C01 + w0 * w2 * C02 + w1 * w2 * C12);
        double sc = (double)gamma[t] / sqrt(var + 1e-5);
        s1t1[t]      = (float)sc;
        s1t1[64 + t] = (float)((double)beta[t] - mean * sc);
    }
}

// ---------------- K3: Gram accumulation  G = sum a a^T, sum a ----------------
// grid 256, block 256; block handles 1024 samples in 16 chunks of 64
__global__ __launch_bounds__(256) void gram_kernel(const float* __restrict__ rel,
        const float* __restrict__ W1, const float* __restrict__ b1,
        const float* __restrict__ s1t1, unsigned long long* __restrict__ Gfix) {
    __shared__ float  A[64][68];     // row stride 272 B = 17x16 -> float4-aligned
    __shared__ float4 W1l[64];
    __shared__ float2 st1[64];
    const int tid = threadIdx.x;
    const int lane = tid & 63, wave = tid >> 6;
    if (tid < 64) {
        W1l[tid] = make_float4(W1[tid * 3], W1[tid * 3 + 1], W1[tid * 3 + 2], b1[tid]);
        st1[tid] = make_float2(s1t1[tid], s1t1[64 + tid]);
    }
    __syncthreads();

    const int i0 = (tid >> 4) * 4, j0 = (tid & 15) * 4;
    float g[4][4];
#pragma unroll
    for (int a = 0; a < 4; ++a)
#pragma unroll
        for (int c = 0; c < 4; ++c) g[a][c] = 0.f;
    float4 sa4[4];
#pragma unroll
    for (int i = 0; i < 4; ++i) sa4[i] = make_float4(0.f, 0.f, 0.f, 0.f);

#pragma unroll 1
    for (int ch = 0; ch < 16; ++ch) {
        // phase 1: a for 64 samples (lane = sample, wave = its 16-channel block)
        const int s = (blockIdx.x * 16 + ch) * 64 + lane;
        float r0 = rel[s * 3], r1 = rel[s * 3 + 1], r2 = rel[s * 3 + 2];
#pragma unroll
        for (int i = 0; i < 4; ++i) {
            const int c0 = wave * 16 + i * 4;
            float4 av;
            {
                float4 w = W1l[c0];     float2 st = st1[c0];
                av.x = fmaxf(fmaf(st.x, (w.x * r0 + w.y * r1 + w.z * r2) + w.w, st.y), 0.f);
            }
            {
                float4 w = W1l[c0 + 1]; float2 st = st1[c0 + 1];
                av.y = fmaxf(fmaf(st.x, (w.x * r0 + w.y * r1 + w.z * r2) + w.w, st.y), 0.f);
            }
            {
                float4 w = W1l[c0 + 2]; float2 st = st1[c0 + 2];
                av.z = fmaxf(fmaf(st.x, (w.x * r0 + w.y * r1 + w.z * r2) + w.w, st.y), 0.f);
            }
            {
                float4 w = W1l[c0 + 3]; float2 st = st1[c0 + 3];
                av.w = fmaxf(fmaf(st.x, (w.x * r0 + w.y * r1 + w.z * r2) + w.w, st.y), 0.f);
            }
            *(float4*)&A[lane][c0] = av;
            sa4[i].x += av.x; sa4[i].y += av.y; sa4[i].z += av.z; sa4[i].w += av.w;
        }
        __syncthreads();
        // phase 2: 4x4 Gram tile over the 64 staged samples
#pragma unroll 4
        for (int sl = 0; sl < 64; ++sl) {
            float4 ai = *(const float4*)&A[sl][i0];
            float4 aj = *(const float4*)&A[sl][j0];
            g[0][0] = fmaf(ai.x, aj.x, g[0][0]); g[0][1] = fmaf(ai.x, aj.y, g[0][1]);
            g[0][2] = fmaf(ai.x, aj.z, g[0][2]); g[0][3] = fmaf(ai.x, aj.w, g[0][3]);
            g[1][0] = fmaf(ai.y, aj.x, g[1][0]); g[1][1] = fmaf(ai.y, aj.y, g[1][1]);
            g[1][2] = fmaf(ai.y, aj.z, g[1][2]); g[1][3] = fmaf(ai.y, aj.w, g[1][3]);
            g[2][0] = fmaf(ai.z, aj.x, g[2][0]); g[2][1] = fmaf(ai.z, aj.y, g[2][1]);
            g[2][2] = fmaf(ai.z, aj.z, g[2][2]); g[2][3] = fmaf(ai.z, aj.w, g[2][3]);
            g[3][0] = fmaf(ai.w, aj.x, g[3][0]); g[3][1] = fmaf(ai.w, aj.y, g[3][1]);
            g[3][2] = fmaf(ai.w, aj.z, g[3][2]); g[3][3] = fmaf(ai.w, aj.w, g[3][3]);
        }
        __syncthreads();
    }
    // deterministic fixed-point atomic accumulation (all values >= 0 post-ReLU)
#pragma unroll
    for (int a = 0; a < 4; ++a)
#pragma unroll
        for (int c = 0; c < 4; ++c)
            atomicAdd(&Gfix[(i0 + a) * 64 + (j0 + c)],
                      (unsigned long long)((double)g[a][c] * FIXSCALE));
#pragma unroll
    for (int i = 0; i < 4; ++i) {
        float4 v = sa4[i];
#pragma unroll
        for (int d = 1; d < 64; d <<= 1) {
            v.x += __shfl_xor(v.x, d, 64); v.y += __shfl_xor(v.y, d, 64);
            v.z += __shfl_xor(v.z, d, 64); v.w += __shfl_xor(v.w, d, 64);
        }
        if (lane == 0) {
            const int c0 = wave * 16 + i * 4;
            atomicAdd(&Gfix[4096 + c0 + 0], (unsigned long long)((double)v.x * FIXSCALE));
            atomicAdd(&Gfix[4096 + c0 + 1], (unsigned long long)((double)v.y * FIXSCALE));
            atomicAdd(&Gfix[4096 + c0 + 2], (unsigned long long)((double)v.z * FIXSCALE));
            atomicAdd(&Gfix[4096 + c0 + 3], (unsigned long long)((double)v.w * FIXSCALE));
        }
    }
}

// ---------------- K4: finalize BN2 affine from G ----------------
// grid 1, block 1024. LDS rows padded to 68 floats (16 B-aligned float4 reads).
__global__ __launch_bounds__(1024) void fin2G_kernel(const unsigned long long* __restrict__ Gfix,
                            const float* __restrict__ W2, const float* __restrict__ b2,
                            const float* __restrict__ gamma, const float* __restrict__ beta,
                            float* __restrict__ s2t2) {
    __shared__ float Gs[64][68];
    __shared__ float w2s[64][68];
    __shared__ float sa_s[64];
    __shared__ float red[16][64];
    const int tid = threadIdx.x;
    const double INV = 1.0 / FIXSCALE;
    for (int i = tid; i < 4096; i += 1024) {
        Gs[i >> 6][i & 63]  = (float)((double)Gfix[i] * INV);
        w2s[i >> 6][i & 63] = W2[i];
    }
    if (tid < 64) sa_s[tid] = (float)((double)Gfix[4096 + tid] * INV);
    __syncthreads();

    const int o = tid & 63, part = tid >> 6;   // 16 parts x 4 rows each
    float partial = 0.f;
#pragma unroll
    for (int ii = 0; ii < 4; ++ii) {
        const int i = part * 4 + ii;
        float t = 0.f;
#pragma unroll
        for (int j = 0; j < 64; j += 4) {
            float4 wj = *(const float4*)&w2s[o][j];
            float4 gj = *(const float4*)&Gs[i][j];
            t = fmaf(wj.x, gj.x, t); t = fmaf(wj.y, gj.y, t);
            t = fmaf(wj.z, gj.z, t); t = fmaf(wj.w, gj.w, t);
        }
        partial = fmaf(w2s[o][i], t, partial);
    }
    red[part][o] = partial;
    __syncthreads();
    if (tid < 64) {
        double qf = 0.0;
#pragma unroll
        for (int p = 0; p < 16; ++p) qf += (double)red[p][tid];
        double SA = 0.0;
        for (int c = 0; c < 64; ++c) SA += (double)w2s[tid][c] * (double)sa_s[c];
        const double Md = (double)M_SAMPLES;
        double mean = SA / Md + (double)b2[tid];
        double var  = qf / Md - (SA / Md) * (SA / Md);
        double sc = (double)gamma[tid] / sqrt(var + 1e-5);
        s2t2[tid]      = (float)sc;
        s2t2[64 + tid] = (float)((double)beta[tid] - mean * sc);
    }
}

// ---------------- K5: full chain + max over k, write [B,C,N] (R2-verbatim) -------------
__global__ __launch_bounds__(256) void out_kernel(const float* __restrict__ rel,
        const float* __restrict__ W1, const float* __restrict__ b1,
        const float* __restrict__ W2, const float* __restrict__ b2,
        const float* __restrict__ s1t1, const float* __restrict__ s2t2,
        float* __restrict__ out) {
    __shared__ float  W2l[64 * 64];
    __shared__ float4 W1l[64];
    __shared__ float2 st1[64];
    __shared__ float2 st2[64];
    __shared__ float  b2l[64];
    const int tid = threadIdx.x;
    for (int i = tid; i < 4096; i += 256) W2l[i] = W2[i];
    if (tid < 64) {
        W1l[tid] = make_float4(W1[tid * 3], W1[tid * 3 + 1], W1[tid * 3 + 2], b1[tid]);
        st1[tid] = make_float2(s1t1[tid], s1t1[64 + tid]);
        st2[tid] = make_float2(s2t2[tid], s2t2[64 + tid]);
        b2l[tid] = b2[tid];
    }
    __syncthreads();
    const int s = blockIdx.x * 256 + tid;
    float r0 = rel[s * 3], r1 = rel[s * 3 + 1], r2 = rel[s * 3 + 2];
    float a[64];
#pragma unroll
    for (int c = 0; c < 64; ++c) {
        float4 w = W1l[c];
        float h = (w.x * r0 + w.y * r1 + w.z * r2) + w.w;
        float2 st = st1[c];
        a[c] = fmaxf(fmaf(st.x, h, st.y), 0.f);
    }
    float a2[64];
#pragma unroll
    for (int o = 0; o < 64; ++o) {
        float h2 = b2l[o];
#pragma unroll
        for (int c = 0; c < 64; c += 4) {
            float4 w = *(const float4*)&W2l[o * 64 + c];
            h2 = fmaf(w.x, a[c], h2);     h2 = fmaf(w.y, a[c + 1], h2);
            h2 = fmaf(w.z, a[c + 2], h2); h2 = fmaf(w.w, a[c + 3], h2);
        }
        float2 st = st2[o];
        a2[o] = fmaxf(fmaf(st.x, h2, st.y), 0.f);
    }
    const int kk = s & 15;
    const int n  = (s >> 4) & (NPTS - 1);
    const int bb = s >> 15;
#pragma unroll 1
    for (int o = 0; o < 64; ++o) {
        float h3 = b2l[o];
#pragma unroll
        for (int c = 0; c < 64; c += 4) {
            float4 w = *(const float4*)&W2l[o * 64 + c];
            h3 = fmaf(w.x, a2[c], h3);     h3 = fmaf(w.y, a2[c + 1], h3);
            h3 = fmaf(w.z, a2[c + 2], h3); h3 = fmaf(w.w, a2[c + 3], h3);
        }
        h3 = fmaxf(h3, __shfl_xor(h3, 1, 64));
        h3 = fmaxf(h3, __shfl_xor(h3, 2, 64));
        h3 = fmaxf(h3, __shfl_xor(h3, 4, 64));
        h3 = fmaxf(h3, __shfl_xor(h3, 8, 64));
        if (kk == 0) out[(size_t)bb * (CH * NPTS) + o * NPTS + n] = h3;
    }
}

extern "C" void kernel_launch(void* const* d_in, const int* in_sizes, int n_in,
                              void* d_out, int out_size, void* d_ws, size_t ws_size,
                              hipStream_t stream) {
    (void)in_sizes; (void)n_in; (void)out_size; (void)ws_size;
    const float* xyz   = (const float*)d_in[0];
    const float* W1    = (const float*)d_in[1];
    const float* b1    = (const float*)d_in[2];
    const float* W2    = (const float*)d_in[3];
    const float* b2    = (const float*)d_in[4];
    const float* gamma = (const float*)d_in[5];
    const float* beta  = (const float*)d_in[6];
    float* out = (float*)d_out;
    float* ws  = (float*)d_ws;

    float* rel   = ws + WS_REL;
    float* s1t1  = ws + WS_S1T1;
    float* s2t2  = ws + WS_S2T2;
    float* part1 = ws + WS_PART1;
    unsigned long long* Gfix = (unsigned long long*)(ws + WS_GFIX);  // aliases part1

    knn_rel_kernel<<<dim3(4096), dim3(256), 0, stream>>>(xyz, rel, part1);
    fin1_kernel<<<dim3(1), dim3(256), 0, stream>>>(part1, W1, b1, gamma, beta, s1t1, Gfix);
    gram_kernel<<<dim3(256), dim3(256), 0, stream>>>(rel, W1, b1, s1t1, Gfix);
    fin2G_kernel<<<dim3(1), dim3(1024), 0, stream>>>(Gfix, W2, b2, gamma, beta, s2t2);
    out_kernel<<<dim3(1024), dim3(256), 0, stream>>>(rel, W1, b1, W2, b2, s1t1, s2t2, out);
}

// Round 9
// 244.395 us; speedup vs baseline: 5.6456x; 1.1980x over previous
//
#include <hip/hip_runtime.h>
#include <math.h>

#define BATCH 8
#define NPTS 2048
#define CH 64
#define KNB 16
#define M_SAMPLES (BATCH * NPTS * KNB)   // 262144
#define FIXSCALE 1048576.0               // 2^20 fixed-point for deterministic atomics

// ws layout (float offsets) — peak 823552 floats = 3.29 MB (unchanged):
//   rel   : [0, 786432)          262144 * 3 f32
//   s1t1  : [786432, 786560)
//   s2t2  : [786560, 786688)
//   part1 : [786688, 823552)     4096 blocks * 9  (knn -> fin1; dead after fin1)
//   Gfix  : [786688, 795008)     4160 u64, aliases part1 (zeroed in fin1 AFTER
//                                part1 is consumed; gram accumulates; fin2G reads)
#define WS_REL   0
#define WS_S1T1  786432
#define WS_S2T2  786560
#define WS_PART1 786688
#define WS_GFIX  786688

#define SURV_CAP 192
#define D2_EPS 1e-4f

__device__ __forceinline__ unsigned long long u64min(unsigned long long a, unsigned long long b) { return a < b ? a : b; }
__device__ __forceinline__ unsigned long long u64max(unsigned long long a, unsigned long long b) { return a > b ? a : b; }

__device__ __forceinline__ unsigned long long bitonic64(unsigned long long v, int lane) {
#pragma unroll
    for (int k = 2; k <= 64; k <<= 1)
#pragma unroll
        for (int d = k >> 1; d >= 1; d >>= 1) {
            unsigned long long o = __shfl_xor(v, d, 64);
            bool keepmin = (((lane & d) == 0) == ((lane & k) == 0));
            v = keepmin ? u64min(v, o) : u64max(v, o);
        }
    return v;
}

__device__ __forceinline__ unsigned long long cand_key(const float4 pq, const float4 pj, int j, int q) {
    float dot = pq.x * pj.x + pq.y * pj.y + pq.z * pj.z;
    float d2 = fmaxf((pq.w + pj.w) - 2.0f * dot, 0.0f);
    unsigned long long key = ((unsigned long long)__float_as_uint(d2) << 32) | (unsigned int)j;
    return (j == q) ? ~0ull : key;
}

// ---------------- K1: KNN (R7-verbatim, proven) ----------------
__global__ __launch_bounds__(256) void knn_rel_kernel(const float* __restrict__ xyz,
                                                      float* __restrict__ rel,
                                                      float* __restrict__ part1) {
    __shared__ float4 pts[NPTS];
    __shared__ unsigned long long surv[4][SURV_CAP];
    __shared__ unsigned int wavecnt[4];
    __shared__ float red9[4][9];

    const int b     = blockIdx.x >> 9;
    const int qbase = (blockIdx.x & 511) * 4;
    const int tid   = threadIdx.x;
    const int wave  = tid >> 6, lane = tid & 63;

    const float* xb = xyz + (size_t)b * 3 * NPTS;
    for (int j = tid; j < NPTS; j += 256) {
        float x = xb[j], y = xb[NPTS + j], z = xb[2 * NPTS + j];
        pts[j] = make_float4(x, y, z, (x * x + y * y) + z * z);
    }
    __syncthreads();

    const int q = qbase + wave;
    const float4 pq = pts[q];

    unsigned long long lm = ~0ull;
#pragma unroll
    for (int t = 0; t < 32; ++t) {
        const int j = t * 64 + lane;
        lm = u64min(lm, cand_key(pq, pts[j], j, q));
    }
    unsigned long long sorted = bitonic64(lm, lane);
    const float Td2 = __uint_as_float((unsigned int)(__shfl(sorted, 15, 64) >> 32)) + D2_EPS;

    if (lane == 0) wavecnt[wave] = 0u;
#pragma unroll
    for (int t = 0; t < 32; ++t) {
        const int j = t * 64 + lane;
        unsigned long long key = cand_key(pq, pts[j], j, q);
        float d2 = __uint_as_float((unsigned int)(key >> 32));
        if (d2 <= Td2) {
            unsigned int pos = atomicAdd(&wavecnt[wave], 1u);
            if (pos < SURV_CAP) surv[wave][pos] = key;
        }
    }
    const unsigned int total = wavecnt[wave];

    unsigned long long wkey = ~0ull;
    bool ok = false;
    if (total >= 16u && total <= 64u) {
        unsigned long long s0 = (lane < (int)total) ? surv[wave][lane] : ~0ull;
        wkey = bitonic64(s0, lane);
        unsigned long long nxt = __shfl_down(wkey, 1, 64);
        ok = __all((lane == 63) || (wkey <= nxt)) != 0;
    }
    if (!ok) {
        unsigned long long last = 0ull; bool first = true;
#pragma unroll 1
        for (int r = 0; r < 16; ++r) {
            unsigned long long m = ~0ull;
#pragma unroll
            for (int t = 0; t < 32; ++t) {
                const int j = t * 64 + lane;
                unsigned long long key = cand_key(pq, pts[j], j, q);
                if (first || key > last) m = u64min(m, key);
            }
#pragma unroll
            for (int d = 1; d < 64; d <<= 1) m = u64min(m, __shfl_xor(m, d, 64));
            if (lane == r) wkey = m;
            last = m; first = false;
        }
    }

    float rr0 = 0.f, rr1 = 0.f, rr2 = 0.f;
    if (lane < 16) {
        const int j = ((int)(unsigned int)wkey) & (NPTS - 1);
        float4 pn = pts[j];
        rr0 = pn.x - pq.x; rr1 = pn.y - pq.y; rr2 = pn.z - pq.z;
        const size_t relbase = ((size_t)(b * NPTS + q)) * (KNB * 3);
        rel[relbase + lane * 3 + 0] = rr0;
        rel[relbase + lane * 3 + 1] = rr1;
        rel[relbase + lane * 3 + 2] = rr2;
    }
    float m0 = rr0, m1 = rr1, m2 = rr2;
    float m3 = rr0 * rr0, m4 = rr0 * rr1, m5 = rr0 * rr2;
    float m6 = rr1 * rr1, m7 = rr1 * rr2, m8 = rr2 * rr2;
#pragma unroll
    for (int d = 1; d < 64; d <<= 1) {
        m0 += __shfl_xor(m0, d, 64); m1 += __shfl_xor(m1, d, 64); m2 += __shfl_xor(m2, d, 64);
        m3 += __shfl_xor(m3, d, 64); m4 += __shfl_xor(m4, d, 64); m5 += __shfl_xor(m5, d, 64);
        m6 += __shfl_xor(m6, d, 64); m7 += __shfl_xor(m7, d, 64); m8 += __shfl_xor(m8, d, 64);
    }
    if (lane == 0) {
        red9[wave][0] = m0; red9[wave][1] = m1; red9[wave][2] = m2;
        red9[wave][3] = m3; red9[wave][4] = m4; red9[wave][5] = m5;
        red9[wave][6] = m6; red9[wave][7] = m7; red9[wave][8] = m8;
    }
    __syncthreads();
    if (tid < 9)
        part1[blockIdx.x * 9 + tid] =
            red9[0][tid] + red9[1][tid] + red9[2][tid] + red9[3][tid];
}

// ---------------- K2: finalize BN1 affine + zero Gfix (R8-verbatim) --------
__global__ __launch_bounds__(256) void fin1_kernel(const float* __restrict__ part1,
                            const float* __restrict__ W1, const float* __restrict__ b1,
                            const float* __restrict__ gamma, const float* __restrict__ beta,
                            float* __restrict__ s1t1, unsigned long long* __restrict__ Gfix) {
    __shared__ double red[9][256];
    __shared__ double sm[9];
    const int t = threadIdx.x;
    double s[9] = {0, 0, 0, 0, 0, 0, 0, 0, 0};
    for (int blk = t; blk < 4096; blk += 256)
#pragma unroll
        for (int v = 0; v < 9; ++v) s[v] += (double)part1[blk * 9 + v];
#pragma unroll
    for (int v = 0; v < 9; ++v) red[v][t] = s[v];
    __syncthreads();
    for (int i = t; i < 4160; i += 256) Gfix[i] = 0ull;
    if (t < 9) {
        double x = 0.0;
        for (int i = 0; i < 256; ++i) x += red[t][i];
        sm[t] = x;
    }
    __syncthreads();
    if (t < 64) {
        const double Md = (double)M_SAMPLES;
        double mu0 = sm[0] / Md, mu1 = sm[1] / Md, mu2 = sm[2] / Md;
        double C00 = sm[3] / Md - mu0 * mu0;
        double C01 = sm[4] / Md - mu0 * mu1;
        double C02 = sm[5] / Md - mu0 * mu2;
        double C11 = sm[6] / Md - mu1 * mu1;
        double C12 = sm[7] / Md - mu1 * mu2;
        double C22 = sm[8] / Md - mu2 * mu2;
        double w0 = (double)W1[t * 3], w1 = (double)W1[t * 3 + 1], w2 = (double)W1[t * 3 + 2];
        double mean = w0 * mu0 + w1 * mu1 + w2 * mu2 + (double)b1[t];
        double var  = w0 * w0 * C00 + w1 * w1 * C11 + w2 * w2 * C22
                    + 2.0 * (w0 * w1 * C01 + w0 * w2 * C02 + w1 * w2 * C12);
        double sc = (double)gamma[t] / sqrt(var + 1e-5);
        s1t1[t]      = (float)sc;
        s1t1[64 + t] = (float)((double)beta[t] - mean * sc);
    }
}

// ---------------- K3: Gram accumulation (R8-verbatim) ----------------
__global__ __launch_bounds__(256) void gram_kernel(const float* __restrict__ rel,
        const float* __restrict__ W1, const float* __restrict__ b1,
        const float* __restrict__ s1t1, unsigned long long* __restrict__ Gfix) {
    __shared__ float  A[64][68];
    __shared__ float4 W1l[64];
    __shared__ float2 st1[64];
    const int tid = threadIdx.x;
    const int lane = tid & 63, wave = tid >> 6;
    if (tid < 64) {
        W1l[tid] = make_float4(W1[tid * 3], W1[tid * 3 + 1], W1[tid * 3 + 2], b1[tid]);
        st1[tid] = make_float2(s1t1[tid], s1t1[64 + tid]);
    }
    __syncthreads();

    const int i0 = (tid >> 4) * 4, j0 = (tid & 15) * 4;
    float g[4][4];
#pragma unroll
    for (int a = 0; a < 4; ++a)
#pragma unroll
        for (int c = 0; c < 4; ++c) g[a][c] = 0.f;
    float4 sa4[4];
#pragma unroll
    for (int i = 0; i < 4; ++i) sa4[i] = make_float4(0.f, 0.f, 0.f, 0.f);

#pragma unroll 1
    for (int ch = 0; ch < 16; ++ch) {
        const int s = (blockIdx.x * 16 + ch) * 64 + lane;
        float r0 = rel[s * 3], r1 = rel[s * 3 + 1], r2 = rel[s * 3 + 2];
#pragma unroll
        for (int i = 0; i < 4; ++i) {
            const int c0 = wave * 16 + i * 4;
            float4 av;
            {
                float4 w = W1l[c0];     float2 st = st1[c0];
                av.x = fmaxf(fmaf(st.x, (w.x * r0 + w.y * r1 + w.z * r2) + w.w, st.y), 0.f);
            }
            {
                float4 w = W1l[c0 + 1]; float2 st = st1[c0 + 1];
                av.y = fmaxf(fmaf(st.x, (w.x * r0 + w.y * r1 + w.z * r2) + w.w, st.y), 0.f);
            }
            {
                float4 w = W1l[c0 + 2]; float2 st = st1[c0 + 2];
                av.z = fmaxf(fmaf(st.x, (w.x * r0 + w.y * r1 + w.z * r2) + w.w, st.y), 0.f);
            }
            {
                float4 w = W1l[c0 + 3]; float2 st = st1[c0 + 3];
                av.w = fmaxf(fmaf(st.x, (w.x * r0 + w.y * r1 + w.z * r2) + w.w, st.y), 0.f);
            }
            *(float4*)&A[lane][c0] = av;
            sa4[i].x += av.x; sa4[i].y += av.y; sa4[i].z += av.z; sa4[i].w += av.w;
        }
        __syncthreads();
#pragma unroll 4
        for (int sl = 0; sl < 64; ++sl) {
            float4 ai = *(const float4*)&A[sl][i0];
            float4 aj = *(const float4*)&A[sl][j0];
            g[0][0] = fmaf(ai.x, aj.x, g[0][0]); g[0][1] = fmaf(ai.x, aj.y, g[0][1]);
            g[0][2] = fmaf(ai.x, aj.z, g[0][2]); g[0][3] = fmaf(ai.x, aj.w, g[0][3]);
            g[1][0] = fmaf(ai.y, aj.x, g[1][0]); g[1][1] = fmaf(ai.y, aj.y, g[1][1]);
            g[1][2] = fmaf(ai.y, aj.z, g[1][2]); g[1][3] = fmaf(ai.y, aj.w, g[1][3]);
            g[2][0] = fmaf(ai.z, aj.x, g[2][0]); g[2][1] = fmaf(ai.z, aj.y, g[2][1]);
            g[2][2] = fmaf(ai.z, aj.z, g[2][2]); g[2][3] = fmaf(ai.z, aj.w, g[2][3]);
            g[3][0] = fmaf(ai.w, aj.x, g[3][0]); g[3][1] = fmaf(ai.w, aj.y, g[3][1]);
            g[3][2] = fmaf(ai.w, aj.z, g[3][2]); g[3][3] = fmaf(ai.w, aj.w, g[3][3]);
        }
        __syncthreads();
    }
#pragma unroll
    for (int a = 0; a < 4; ++a)
#pragma unroll
        for (int c = 0; c < 4; ++c)
            atomicAdd(&Gfix[(i0 + a) * 64 + (j0 + c)],
                      (unsigned long long)((double)g[a][c] * FIXSCALE));
#pragma unroll
    for (int i = 0; i < 4; ++i) {
        float4 v = sa4[i];
#pragma unroll
        for (int d = 1; d < 64; d <<= 1) {
            v.x += __shfl_xor(v.x, d, 64); v.y += __shfl_xor(v.y, d, 64);
            v.z += __shfl_xor(v.z, d, 64); v.w += __shfl_xor(v.w, d, 64);
        }
        if (lane == 0) {
            const int c0 = wave * 16 + i * 4;
            atomicAdd(&Gfix[4096 + c0 + 0], (unsigned long long)((double)v.x * FIXSCALE));
            atomicAdd(&Gfix[4096 + c0 + 1], (unsigned long long)((double)v.y * FIXSCALE));
            atomicAdd(&Gfix[4096 + c0 + 2], (unsigned long long)((double)v.z * FIXSCALE));
            atomicAdd(&Gfix[4096 + c0 + 3], (unsigned long long)((double)v.w * FIXSCALE));
        }
    }
}

// ---------------- K4: finalize BN2 affine from G (R8-verbatim) ----------------
__global__ __launch_bounds__(1024) void fin2G_kernel(const unsigned long long* __restrict__ Gfix,
                            const float* __restrict__ W2, const float* __restrict__ b2,
                            const float* __restrict__ gamma, const float* __restrict__ beta,
                            float* __restrict__ s2t2) {
    __shared__ float Gs[64][68];
    __shared__ float w2s[64][68];
    __shared__ float sa_s[64];
    __shared__ float red[16][64];
    const int tid = threadIdx.x;
    const double INV = 1.0 / FIXSCALE;
    for (int i = tid; i < 4096; i += 1024) {
        Gs[i >> 6][i & 63]  = (float)((double)Gfix[i] * INV);
        w2s[i >> 6][i & 63] = W2[i];
    }
    if (tid < 64) sa_s[tid] = (float)((double)Gfix[4096 + tid] * INV);
    __syncthreads();

    const int o = tid & 63, part = tid >> 6;
    float partial = 0.f;
#pragma unroll
    for (int ii = 0; ii < 4; ++ii) {
        const int i = part * 4 + ii;
        float t = 0.f;
#pragma unroll
        for (int j = 0; j < 64; j += 4) {
            float4 wj = *(const float4*)&w2s[o][j];
            float4 gj = *(const float4*)&Gs[i][j];
            t = fmaf(wj.x, gj.x, t); t = fmaf(wj.y, gj.y, t);
            t = fmaf(wj.z, gj.z, t); t = fmaf(wj.w, gj.w, t);
        }
        partial = fmaf(w2s[o][i], t, partial);
    }
    red[part][o] = partial;
    __syncthreads();
    if (tid < 64) {
        double qf = 0.0;
#pragma unroll
        for (int p = 0; p < 16; ++p) qf += (double)red[p][tid];
        double SA = 0.0;
        for (int c = 0; c < 64; ++c) SA += (double)w2s[tid][c] * (double)sa_s[c];
        const double Md = (double)M_SAMPLES;
        double mean = SA / Md + (double)b2[tid];
        double var  = qf / Md - (SA / Md) * (SA / Md);
        double sc = (double)gamma[tid] / sqrt(var + 1e-5);
        s2t2[tid]      = (float)sc;
        s2t2[64 + tid] = (float)((double)beta[tid] - mean * sc);
    }
}

// ---------------- K5: block-GEMM chain + max over k, write [B,C,N] ----------------
// grid 4096 (64 samples/block), block 256. Register-tiled 4x4 GEMMs:
// 8 ds_read_b128 per 64 FMA (vs 1:4 before) -> FMA-bound.
#define FMA4(cv, s, wv) { cv.x = fmaf(s, wv.x, cv.x); cv.y = fmaf(s, wv.y, cv.y); \
                          cv.z = fmaf(s, wv.z, cv.z); cv.w = fmaf(s, wv.w, cv.w); }
__global__ __launch_bounds__(256) void out_kernel(const float* __restrict__ rel,
        const float* __restrict__ W1, const float* __restrict__ b1,
        const float* __restrict__ W2, const float* __restrict__ b2,
        const float* __restrict__ s1t1, const float* __restrict__ s2t2,
        float* __restrict__ out) {
    __shared__ float  W2T[64][68];   // W2T[k][j] = W2[j][k]; rows 16B-aligned
    __shared__ float  A[64][68];     // activations, reused for a and a2
    __shared__ float4 W1l[64];
    __shared__ float2 st1[64];
    __shared__ float2 st2[64];
    __shared__ float  b2l[64];
    __shared__ float  Mred[1024];    // [n(4)][d(4)][jj(16)] float4 over dj

    const int tid = threadIdx.x;
    const int lane = tid & 63, wave = tid >> 6;
    const int sbase = blockIdx.x * 64;

    for (int i = tid; i < 4096; i += 256) W2T[i & 63][i >> 6] = W2[i];
    if (tid < 64) {
        W1l[tid] = make_float4(W1[tid * 3], W1[tid * 3 + 1], W1[tid * 3 + 2], b1[tid]);
        st1[tid] = make_float2(s1t1[tid], s1t1[64 + tid]);
        st2[tid] = make_float2(s2t2[tid], s2t2[64 + tid]);
        b2l[tid] = b2[tid];
    }
    // rel loads issued early (all 4 waves read the same 64 samples; L1 broadcast)
    const int s = sbase + lane;
    float r0 = rel[s * 3], r1 = rel[s * 3 + 1], r2 = rel[s * 3 + 2];
    __syncthreads();

    // phase A: a for 64 samples (lane = sample, wave = its 16-channel block)
#pragma unroll
    for (int i = 0; i < 4; ++i) {
        const int c0 = wave * 16 + i * 4;
        float4 av;
        {
            float4 w = W1l[c0];     float2 st = st1[c0];
            av.x = fmaxf(fmaf(st.x, (w.x * r0 + w.y * r1 + w.z * r2) + w.w, st.y), 0.f);
        }
        {
            float4 w = W1l[c0 + 1]; float2 st = st1[c0 + 1];
            av.y = fmaxf(fmaf(st.x, (w.x * r0 + w.y * r1 + w.z * r2) + w.w, st.y), 0.f);
        }
        {
            float4 w = W1l[c0 + 2]; float2 st = st1[c0 + 2];
            av.z = fmaxf(fmaf(st.x, (w.x * r0 + w.y * r1 + w.z * r2) + w.w, st.y), 0.f);
        }
        {
            float4 w = W1l[c0 + 3]; float2 st = st1[c0 + 3];
            av.w = fmaxf(fmaf(st.x, (w.x * r0 + w.y * r1 + w.z * r2) + w.w, st.y), 0.f);
        }
        *(float4*)&A[lane][c0] = av;
    }
    __syncthreads();

    const int i0 = (tid >> 4) * 4;   // sample rows (within same k-group of 16)
    const int j0 = (tid & 15) * 4;   // output channels
    const float4 bj = make_float4(b2l[j0], b2l[j0 + 1], b2l[j0 + 2], b2l[j0 + 3]);

    // GEMM1: c[di] = A[i0+di][:] . W2T[:][j0..j0+3]
    float4 c0v = {0, 0, 0, 0}, c1v = {0, 0, 0, 0}, c2v = {0, 0, 0, 0}, c3v = {0, 0, 0, 0};
#pragma unroll
    for (int k4 = 0; k4 < 16; ++k4) {
        const int k = k4 * 4;
        float4 a0 = *(const float4*)&A[i0 + 0][k];
        float4 a1 = *(const float4*)&A[i0 + 1][k];
        float4 a2 = *(const float4*)&A[i0 + 2][k];
        float4 a3 = *(const float4*)&A[i0 + 3][k];
        float4 w0 = *(const float4*)&W2T[k + 0][j0];
        float4 w1 = *(const float4*)&W2T[k + 1][j0];
        float4 w2 = *(const float4*)&W2T[k + 2][j0];
        float4 w3 = *(const float4*)&W2T[k + 3][j0];
        FMA4(c0v, a0.x, w0) FMA4(c0v, a0.y, w1) FMA4(c0v, a0.z, w2) FMA4(c0v, a0.w, w3)
        FMA4(c1v, a1.x, w0) FMA4(c1v, a1.y, w1) FMA4(c1v, a1.z, w2) FMA4(c1v, a1.w, w3)
        FMA4(c2v, a2.x, w0) FMA4(c2v, a2.y, w1) FMA4(c2v, a2.z, w2) FMA4(c2v, a2.w, w3)
        FMA4(c3v, a3.x, w0) FMA4(c3v, a3.y, w1) FMA4(c3v, a3.z, w2) FMA4(c3v, a3.w, w3)
    }
    // epilogue 1: a2 = relu(st2*(c+b2)+t2), per output channel j0+dj
    const float2 sA = st2[j0], sB = st2[j0 + 1], sC = st2[j0 + 2], sD = st2[j0 + 3];
#define EPI1(cv) { cv.x = fmaxf(fmaf(sA.x, cv.x + bj.x, sA.y), 0.f); \
                   cv.y = fmaxf(fmaf(sB.x, cv.y + bj.y, sB.y), 0.f); \
                   cv.z = fmaxf(fmaf(sC.x, cv.z + bj.z, sC.y), 0.f); \
                   cv.w = fmaxf(fmaf(sD.x, cv.w + bj.w, sD.y), 0.f); }
    EPI1(c0v) EPI1(c1v) EPI1(c2v) EPI1(c3v)
    __syncthreads();                 // all GEMM1 reads of A complete
    *(float4*)&A[i0 + 0][j0] = c0v;
    *(float4*)&A[i0 + 1][j0] = c1v;
    *(float4*)&A[i0 + 2][j0] = c2v;
    *(float4*)&A[i0 + 3][j0] = c3v;
    __syncthreads();

    // GEMM2 (same tiling, same weights)
    float4 d0v = {0, 0, 0, 0}, d1v = {0, 0, 0, 0}, d2v = {0, 0, 0, 0}, d3v = {0, 0, 0, 0};
#pragma unroll
    for (int k4 = 0; k4 < 16; ++k4) {
        const int k = k4 * 4;
        float4 a0 = *(const float4*)&A[i0 + 0][k];
        float4 a1 = *(const float4*)&A[i0 + 1][k];
        float4 a2 = *(const float4*)&A[i0 + 2][k];
        float4 a3 = *(const float4*)&A[i0 + 3][k];
        float4 w0 = *(const float4*)&W2T[k + 0][j0];
        float4 w1 = *(const float4*)&W2T[k + 1][j0];
        float4 w2 = *(const float4*)&W2T[k + 2][j0];
        float4 w3 = *(const float4*)&W2T[k + 3][j0];
        FMA4(d0v, a0.x, w0) FMA4(d0v, a0.y, w1) FMA4(d0v, a0.z, w2) FMA4(d0v, a0.w, w3)
        FMA4(d1v, a1.x, w0) FMA4(d1v, a1.y, w1) FMA4(d1v, a1.z, w2) FMA4(d1v, a1.w, w3)
        FMA4(d2v, a2.x, w0) FMA4(d2v, a2.y, w1) FMA4(d2v, a2.z, w2) FMA4(d2v, a2.w, w3)
        FMA4(d3v, a3.x, w0) FMA4(d3v, a3.y, w1) FMA4(d3v, a3.z, w2) FMA4(d3v, a3.w, w3)
    }
    // epilogue 2: + b2, then partial max over this thread's 4 k-rows
    float4 pm;
    pm.x = fmaxf(fmaxf(d0v.x, d1v.x), fmaxf(d2v.x, d3v.x)) + bj.x;
    pm.y = fmaxf(fmaxf(d0v.y, d1v.y), fmaxf(d2v.y, d3v.y)) + bj.y;
    pm.z = fmaxf(fmaxf(d0v.z, d1v.z), fmaxf(d2v.z, d3v.z)) + bj.z;
    pm.w = fmaxf(fmaxf(d0v.w, d1v.w), fmaxf(d2v.w, d3v.w)) + bj.w;
    const int nl = i0 >> 4, dd = (i0 >> 2) & 3, jj = tid & 15;
    *(float4*)&Mred[((nl * 4 + dd) * 16 + jj) * 4] = pm;
    __syncthreads();

    // finalize: 256 threads = 4 n x 64 o; max over the 4 d-slots, store [B,C,N]
    {
        const int n = tid >> 6, o = tid & 63;
        float m = Mred[n * 256 + 0 * 64 + o];
        m = fmaxf(m, Mred[n * 256 + 1 * 64 + o]);
        m = fmaxf(m, Mred[n * 256 + 2 * 64 + o]);
        m = fmaxf(m, Mred[n * 256 + 3 * 64 + o]);
        const int sg = sbase + n * 16;               // a sample in this n-group
        const int bb = sg >> 15;
        const int nn = (sg >> 4) & (NPTS - 1);
        out[(size_t)bb * (CH * NPTS) + o * NPTS + nn] = m;
    }
}

extern "C" void kernel_launch(void* const* d_in, const int* in_sizes, int n_in,
                              void* d_out, int out_size, void* d_ws, size_t ws_size,
                              hipStream_t stream) {
    (void)in_sizes; (void)n_in; (void)out_size; (void)ws_size;
    const float* xyz   = (const float*)d_in[0];
    const float* W1    = (const float*)d_in[1];
    const float* b1    = (const float*)d_in[2];
    const float* W2    = (const float*)d_in[3];
    const float* b2    = (const float*)d_in[4];
    const float* gamma = (const float*)d_in[5];
    const float* beta  = (const float*)d_in[6];
    float* out = (float*)d_out;
    float* ws  = (float*)d_ws;

    float* rel   = ws + WS_REL;
    float* s1t1  = ws + WS_S1T1;
    float* s2t2  = ws + WS_S2T2;
    float* part1 = ws + WS_PART1;
    unsigned long long* Gfix = (unsigned long long*)(ws + WS_GFIX);  // aliases part1

    knn_rel_kernel<<<dim3(4096), dim3(256), 0, stream>>>(xyz, rel, part1);
    fin1_kernel<<<dim3(1), dim3(256), 0, stream>>>(part1, W1, b1, gamma, beta, s1t1, Gfix);
    gram_kernel<<<dim3(256), dim3(256), 0, stream>>>(rel, W1, b1, s1t1, Gfix);
    fin2G_kernel<<<dim3(1), dim3(1024), 0, stream>>>(Gfix, W2, b2, gamma, beta, s2t2);
    out_kernel<<<dim3(4096), dim3(256), 0, stream>>>(rel, W1, b1, W2, b2, s1t1, s2t2, out);
}